// Round 4
// baseline (809.357 us; speedup 1.0000x reference)
//
#include <hip/hip_runtime.h>

#define DEFAULT_SCORE -10000.0f

// One 64-lane wave owns 64 consecutive rows. Two phases.
//
// Phase 1 (decision, LANE-PER-ROW): cond(row) = any(score[nbr] > score[row]).
//   Round 0: load the FULL first nidx line (cols 0..15, 4x16B — one HBM fetch,
//            no extra cost vs 16B since HBM granule is the 64B line) + self
//            score; gather 3 neighbour scores (cols 1..3) -> resolves ~75%.
//   Round 1: unresolved lanes gather the remaining 12 scores FROM REGISTERS
//            (no load dependency) -> alive fraction drops to 1/16.
//   Round 2: survivors load cols 16..63 (12x16B issued together) + 48 gathers.
//   Chain depth 3 (was 7): with 64 rows/wave, P(some lane alive) ~= 1 after
//   each early round, so the wave nearly always runs the full chain — its
//   LENGTH, not the per-lane request count, was the exposed-latency term.
//   Also avoids NT re-fetch of the same line (nt = evict-first) that the old
//   4x16B chunked walk risked. Expected gathers/row ~9.
//
// Phase 2 (output, WAVE-COOPERATIVE): the wave's 64 rows are contiguous, so
//   each store instruction covers 1 KB contiguous (4 rows x 256 B; lane =
//   16*sub + c writes row sub, floats 4c..4c+3). Dropped rows (98.4%) write
//   zeros / {row,-1...}; passthrough rows (1.6%) reload dist/nidx via
//   exec-masked NT loads (rare; branch skipped via execz when no lane needs it).
//
// Streaming traffic is non-temporal so the 4 MB score[] table stays L2-hot
// for the gathers. __builtin_nontemporal_* needs native ext_vector types.
// Harness decodes d_out as float32 -> nidx_out written as float-encoded ints.

typedef int   iv4 __attribute__((ext_vector_type(4)));
typedef float fv4 __attribute__((ext_vector_type(4)));

__device__ __forceinline__ float gmax4(const float* __restrict__ score, iv4 a) {
  const float g0 = (a.x >= 0) ? score[a.x] : DEFAULT_SCORE;
  const float g1 = (a.y >= 0) ? score[a.y] : DEFAULT_SCORE;
  const float g2 = (a.z >= 0) ? score[a.z] : DEFAULT_SCORE;
  const float g3 = (a.w >= 0) ? score[a.w] : DEFAULT_SCORE;
  return fmaxf(fmaxf(g0, g1), fmaxf(g2, g3));
}

__global__ __launch_bounds__(256) void dgb_kernel(
    const float* __restrict__ dist,
    const int*   __restrict__ nidx,
    const float* __restrict__ score,
    float*       __restrict__ dist_out,
    float*       __restrict__ nidx_out,
    int V) {
  const int lane = threadIdx.x & 63;
  const int wave = blockIdx.x * (blockDim.x >> 6) + (threadIdx.x >> 6);
  const int wrow0 = wave << 6;  // first of this wave's 64 rows

  // ---------------- Phase 1: decision (lane-per-row) ----------------
  const int row = wrow0 + lane;
  const bool valid = row < V;
  const size_t rb = (size_t)row << 6;
  const iv4* rowp = reinterpret_cast<const iv4*>(nidx + rb);

  // Round 0: whole first line + self score, issued together.
  iv4 a0 = (iv4)(-1), a1 = (iv4)(-1), a2 = (iv4)(-1), a3 = (iv4)(-1);
  float self = 0.0f;
  if (valid) {
    a0 = __builtin_nontemporal_load(rowp);
    a1 = __builtin_nontemporal_load(rowp + 1);
    a2 = __builtin_nontemporal_load(rowp + 2);
    a3 = __builtin_nontemporal_load(rowp + 3);
    self = score[row];  // sequential, cache-hot
  }
  bool done = !valid;  // done == "cond proven true" (or row out of range)
  if (!done) {
    // col 0 is the self index -> only cols 1..3 here
    const float g1 = (a0.y >= 0) ? score[a0.y] : DEFAULT_SCORE;
    const float g2 = (a0.z >= 0) ? score[a0.z] : DEFAULT_SCORE;
    const float g3 = (a0.w >= 0) ? score[a0.w] : DEFAULT_SCORE;
    if (fmaxf(fmaxf(g1, g2), g3) > self) done = true;
  }
  // Round 1: cols 4..15 from registers (no load dependency).
  if (__any(!done)) {
    if (!done) {
      const float m = fmaxf(fmaxf(gmax4(score, a1), gmax4(score, a2)),
                            gmax4(score, a3));
      if (m > self) done = true;
    }
  }
  // Round 2: survivors (~1/16 of rows) read cols 16..63, all loads up-front.
  if (__any(!done)) {
    if (!done) {
      iv4 b[12];
#pragma unroll
      for (int c = 0; c < 12; ++c)
        b[c] = __builtin_nontemporal_load(rowp + 4 + c);
      float m = DEFAULT_SCORE;
#pragma unroll
      for (int c = 0; c < 12; ++c) m = fmaxf(m, gmax4(score, b[c]));
      if (m > self) done = true;
    }
  }
  // done == cond for valid rows; invalid rows are fully guarded below.
  const unsigned long long cbits = __ballot(done && valid);

  // ---------------- Phase 2: output (wave-cooperative) ----------------
  // Store instruction s covers rows 4s..4s+3 fully: 1 KB contiguous.
  const int sub  = lane >> 4;        // row offset within the 4-row group
  const int col0 = (lane & 15) << 2; // starting float column
#pragma unroll 4
  for (int s = 0; s < 16; ++s) {
    const int r = (s << 2) + sub;    // row index within wave, 0..63
    const int orow = wrow0 + r;
    if (wrow0 + (s << 2) >= V) break;  // wave-uniform tail cut
    const bool c = (cbits >> r) & 1ull;
    const size_t off = ((size_t)orow << 6) + col0;

    fv4 d4 = (fv4)(0.0f);
    fv4 n4 = {(col0 == 0) ? (float)orow : -1.0f, -1.0f, -1.0f, -1.0f};
    if (orow < V && !c) {  // ~1.6% of rows: exact passthrough
      d4 = __builtin_nontemporal_load(
          reinterpret_cast<const fv4*>(dist + off));
      const iv4 id = __builtin_nontemporal_load(
          reinterpret_cast<const iv4*>(nidx + off));
      n4 = (fv4){(float)id.x, (float)id.y, (float)id.z, (float)id.w};
    }
    if (orow < V) {
      __builtin_nontemporal_store(d4, reinterpret_cast<fv4*>(dist_out + off));
      __builtin_nontemporal_store(n4, reinterpret_cast<fv4*>(nidx_out + off));
    }
  }
}

extern "C" void kernel_launch(void* const* d_in, const int* in_sizes, int n_in,
                              void* d_out, int out_size, void* d_ws, size_t ws_size,
                              hipStream_t stream) {
  const float* dist  = (const float*)d_in[0];  // [V, 64] f32
  const int*   nidx  = (const int*)d_in[1];    // [V, 64] i32
  const float* score = (const float*)d_in[2];  // [V, 1]  f32

  const int V = in_sizes[2];

  float* dist_out = (float*)d_out;                    // V*64 floats
  float* nidx_out = (float*)d_out + (size_t)V * 64;   // V*64 float-encoded ints

  const int rows_per_block = 4 * 64;  // 4 waves x 64 rows
  const int grid = (V + rows_per_block - 1) / rows_per_block;

  dgb_kernel<<<grid, 256, 0, stream>>>(dist, nidx, score, dist_out, nidx_out, V);
}